// Round 6
// baseline (398.407 us; speedup 1.0000x reference)
//
#include <hip/hip_runtime.h>
#include <hip/hip_bf16.h>

#define DM 1024
#define NH 16
#define DH 64
#define BB 4
#define SS 2048
#define MROWS (BB*SS)   // 8192

typedef unsigned short u16;
typedef short bf16x8 __attribute__((ext_vector_type(8)));
typedef short bf16x4 __attribute__((ext_vector_type(4)));
typedef float f32x4 __attribute__((ext_vector_type(4)));
typedef unsigned uintx2 __attribute__((ext_vector_type(2)));

#define MFMA16(a, b, c) __builtin_amdgcn_mfma_f32_16x16x32_bf16((a), (b), (c), 0, 0, 0)
#define MFMA16K16(a, b, c) __builtin_amdgcn_mfma_f32_16x16x16bf16_1k((a), (b), (c), 0, 0, 0)

__device__ __forceinline__ u16 f2bf(float f) {
  union { float f; unsigned u; } v; v.f = f;
  unsigned u = v.u;
  return (u16)((u + 0x7fffu + ((u >> 16) & 1u)) >> 16);
}

// pack two floats -> one u32 of two RNE bf16 (lo = a, hi = b)
__device__ __forceinline__ unsigned pack2bf(float a, float b) {
  return ((unsigned)f2bf(b) << 16) | (unsigned)f2bf(a);
}

__device__ __forceinline__ bf16x8 ld_bf8(const u16* p) {
  return *(const bf16x8*)p;
}

// ---------------- convert x (fp32 -> bf16), 4 elems/thread ----------------
__global__ __launch_bounds__(256) void k_cvt_x(const float* __restrict__ x,
                                               u16* __restrict__ xb) {
  int i = (blockIdx.x * 256 + threadIdx.x) * 4;
  float4 v = *(const float4*)(x + i);
  ushort4 o;
  o.x = f2bf(v.x); o.y = f2bf(v.y); o.z = f2bf(v.z); o.w = f2bf(v.w);
  *(ushort4*)(xb + i) = o;
}

// ------------- transpose weights W[K,N] -> Wt[N,K] bf16, 4 segments -------
__global__ __launch_bounds__(1024) void k_tw(const float* __restrict__ Wq,
                                             const float* __restrict__ Wk,
                                             const float* __restrict__ Wv,
                                             const float* __restrict__ Wo,
                                             u16* __restrict__ Wt) {
  __shared__ float t[32][33];
  int k0 = blockIdx.x * 32;
  int seg = blockIdx.y >> 5;
  int n0 = (blockIdx.y & 31) * 32;
  const float* W = seg == 0 ? Wq : seg == 1 ? Wk : seg == 2 ? Wv : Wo;
  int tx = threadIdx.x, ty = threadIdx.y;
  t[ty][tx] = W[(size_t)(k0 + ty) * DM + n0 + tx];
  __syncthreads();
  Wt[(size_t)(seg * DM + n0 + ty) * DM + k0 + tx] = f2bf(t[tx][ty]);
}

// ---------------- GEMM: C[M,N] = A[M,K] * Bt[N,K]^T + bias ----------------
// mode 0: write fp32 [M,N] to of, bias b0
// mode 1: N=3072 fused QKV; Q scaled by 0.125*log2(e); V written transposed
//         [B,H,Dh,S]; Q/K written [B,H,S,Dh] bf16.
__global__ __launch_bounds__(256) void k_gemm(
    const u16* __restrict__ A, const u16* __restrict__ Bt,
    int M, int N, int K,
    const float* __restrict__ b0, const float* __restrict__ b1,
    const float* __restrict__ b2,
    u16* __restrict__ oq, u16* __restrict__ ok, u16* __restrict__ ov,
    float* __restrict__ of, int mode) {
  __shared__ __align__(16) u16 As[128][40];
  __shared__ __align__(16) u16 Bs[128][40];
  int tid = threadIdx.x;
  int wave = tid >> 6, lane = tid & 63, quad = lane >> 4, l16 = lane & 15;
  int bm = blockIdx.x * 128, bn = blockIdx.y * 128;
  int wr = (wave >> 1) * 64, wc = (wave & 1) * 64;
  f32x4 acc[4][4] = {};

  for (int k0 = 0; k0 < K; k0 += 32) {
#pragma unroll
    for (int i = 0; i < 2; ++i) {
      int c = i * 256 + tid;          // 0..511
      int r = c >> 2, col = (c & 3) * 8;
      *(bf16x8*)(&As[r][col]) = ld_bf8(A + (size_t)(bm + r) * K + k0 + col);
      *(bf16x8*)(&Bs[r][col]) = ld_bf8(Bt + (size_t)(bn + r) * K + k0 + col);
    }
    __syncthreads();
    bf16x8 af[4], bfr[4];
#pragma unroll
    for (int mi = 0; mi < 4; ++mi)
      af[mi] = *(const bf16x8*)(&As[wr + mi * 16 + l16][quad * 8]);
#pragma unroll
    for (int ni = 0; ni < 4; ++ni)
      bfr[ni] = *(const bf16x8*)(&Bs[wc + ni * 16 + l16][quad * 8]);
#pragma unroll
    for (int mi = 0; mi < 4; ++mi)
#pragma unroll
      for (int ni = 0; ni < 4; ++ni)
        acc[mi][ni] = MFMA16(af[mi], bfr[ni], acc[mi][ni]);
    __syncthreads();
  }

  if (mode == 0) {
#pragma unroll
    for (int mi = 0; mi < 4; ++mi)
#pragma unroll
      for (int ni = 0; ni < 4; ++ni)
#pragma unroll
        for (int r = 0; r < 4; ++r) {
          int row = bm + wr + mi * 16 + quad * 4 + r;
          int col = bn + wc + ni * 16 + l16;
          of[(size_t)row * N + col] = acc[mi][ni][r] + b0[col];
        }
  } else {
    int seg = bn >> 10;  // 128-col block never crosses a 1024 segment
    const float* bia = seg == 0 ? b0 : seg == 1 ? b1 : b2;
    int cb = bn & 1023;
    if (seg == 2) {
      // V transposed: [B,H,Dh,S]; 4 consecutive seq rows -> one 8B store
#pragma unroll
      for (int mi = 0; mi < 4; ++mi)
#pragma unroll
        for (int ni = 0; ni < 4; ++ni) {
          int row = bm + wr + mi * 16 + quad * 4;
          int col = cb + wc + ni * 16 + l16;
          float bv_ = bia[col];
          int bb2 = row >> 11, s = row & 2047, hh = col >> 6, dh = col & 63;
          ushort4 o4;
          o4.x = f2bf(acc[mi][ni][0] + bv_);
          o4.y = f2bf(acc[mi][ni][1] + bv_);
          o4.z = f2bf(acc[mi][ni][2] + bv_);
          o4.w = f2bf(acc[mi][ni][3] + bv_);
          *(ushort4*)(&ov[(((size_t)bb2 * NH + hh) * DH + dh) * SS + s]) = o4;
        }
    } else {
      u16* o = seg == 0 ? oq : ok;
      // fold attention scale AND log2(e) into Q so attn uses exp2 directly
      float sc = seg == 0 ? (0.125f * 1.44269504f) : 1.0f;
#pragma unroll
      for (int mi = 0; mi < 4; ++mi)
#pragma unroll
        for (int ni = 0; ni < 4; ++ni)
#pragma unroll
          for (int r = 0; r < 4; ++r) {
            int row = bm + wr + mi * 16 + quad * 4 + r;
            int col = cb + wc + ni * 16 + l16;
            float v = (acc[mi][ni][r] + bia[col]) * sc;
            int bb2 = row >> 11, s = row & 2047, hh = col >> 6, dh = col & 63;
            o[((((size_t)bb2 * NH + hh) * SS) + s) * DH + dh] = f2bf(v);
          }
    }
  }
}

// ---------------- flash attention (transposed-S, register-resident P) -----
// grid: (S/128, NH, BB), block 256 (4 waves, 32 q-rows each)
// St[kv][q] = K·Q^T via mfma(A=K,B=Q): C-layout col=q=lane&15,
// row=kv=quad*4+reg — which IS the B-operand layout of
// v_mfma_f32_16x16x16_bf16 (k=quad*4+j, n=lane&15). So P feeds PV straight
// from registers: no LDS round-trip, no cross-lane moves.
// PV: O^T[d][q] += V^T(A-frag from LDS [d][kv]) · P(B). O^T C-layout gives
// contiguous d per lane -> 8B output stores.
__global__ __launch_bounds__(256) void k_attn(const u16* __restrict__ Q,
                                              const u16* __restrict__ Kg,
                                              const u16* __restrict__ VT,
                                              u16* __restrict__ ctx) {
  __shared__ __align__(16) u16 Ks[2][64][72];
  __shared__ __align__(16) u16 Vts[2][64][72];  // [d][kv]
  int tid = threadIdx.x;
  int wave = tid >> 6, lane = tid & 63, quad = lane >> 4, l16 = lane & 15;
  int q0 = blockIdx.x * 128;
  int h = blockIdx.y, b = blockIdx.z;
  size_t bh = ((size_t)b * NH + h) * SS * DH;
  const u16* Qp = Q + bh + (size_t)(q0 + wave * 32) * DH;
  const u16* Kp = Kg + bh;
  const u16* Vp = VT + ((size_t)b * NH + h) * DH * SS;  // [Dh][S]

  // Q as B-operand fragments: B[k=d=quad*8+j][n=q=l16], 2 q-tiles
  bf16x8 qf[2][2];
#pragma unroll
  for (int qt = 0; qt < 2; ++qt) {
    qf[qt][0] = ld_bf8(Qp + (qt * 16 + l16) * DH + quad * 8);
    qf[qt][1] = ld_bf8(Qp + (qt * 16 + l16) * DH + 32 + quad * 8);
  }

  f32x4 Ot[4][2] = {};   // [d-tile][q-tile], O^T C-layout
  float lrun[2] = {0.0f, 0.0f};  // per-lane partial sum, q = l16 (per q-tile)

  int sr = tid >> 3;        // 0..31
  int sc = (tid & 7) * 8;   // 0..56

  // prestage tile 0 into buffer 0
#pragma unroll
  for (int i = 0; i < 2; ++i) {
    int r = sr + i * 32;
    *(bf16x8*)(&Ks[0][r][sc]) = ld_bf8(Kp + (size_t)r * DH + sc);
    *(bf16x8*)(&Vts[0][r][sc]) = ld_bf8(Vp + (size_t)r * SS + sc);
  }
  __syncthreads();

  for (int it = 0; it < SS / 64; ++it) {
    int p = it & 1;
    int kv1 = (it + 1) * 64;

    // St = K·Q^T: 4 kv-tiles (m) x 2 q-tiles (n); s pre-scaled via Q
    f32x4 s[2][4];  // [qt][kv-tile]
#pragma unroll
    for (int t = 0; t < 4; ++t) {
      bf16x8 kb0 = *(const bf16x8*)(&Ks[p][t * 16 + l16][quad * 8]);
      bf16x8 kb1 = *(const bf16x8*)(&Ks[p][t * 16 + l16][32 + quad * 8]);
#pragma unroll
      for (int qt = 0; qt < 2; ++qt) {
        f32x4 z = {};
        z = MFMA16(kb0, qf[qt][0], z);
        z = MFMA16(kb1, qf[qt][1], z);
        s[qt][t] = z;
      }
    }

    // stage next KV tile into the other buffer (overlaps with softmax/PV)
    if (kv1 < SS) {
#pragma unroll
      for (int i = 0; i < 2; ++i) {
        int r = sr + i * 32;
        *(bf16x8*)(&Ks[1 - p][r][sc]) =
            ld_bf8(Kp + (size_t)(kv1 + r) * DH + sc);
        *(bf16x8*)(&Vts[1 - p][r][sc]) =
            ld_bf8(Vp + (size_t)r * SS + kv1 + sc);
      }
    }

    // P = exp2(St) in registers; pack to 16x16x16 B-frags; partial sums
    bf16x4 pb[2][4];
#pragma unroll
    for (int qt = 0; qt < 2; ++qt)
#pragma unroll
      for (int t = 0; t < 4; ++t) {
        float e0 = exp2f(s[qt][t][0]);
        float e1 = exp2f(s[qt][t][1]);
        float e2 = exp2f(s[qt][t][2]);
        float e3 = exp2f(s[qt][t][3]);
        lrun[qt] += (e0 + e1) + (e2 + e3);
        uintx2 w;
        w[0] = pack2bf(e0, e1);
        w[1] = pack2bf(e2, e3);
        pb[qt][t] = __builtin_bit_cast(bf16x4, w);
      }

    // PV: O^T[d][q] += V^T · P ; K=16 chunks (c), A = Vts[d][kv] frags
#pragma unroll
    for (int c = 0; c < 4; ++c)
#pragma unroll
      for (int dt = 0; dt < 4; ++dt) {
        bf16x4 va = *(const bf16x4*)(&Vts[p][dt * 16 + l16][c * 16 + quad * 4]);
#pragma unroll
        for (int qt = 0; qt < 2; ++qt)
          Ot[dt][qt] = MFMA16K16(va, pb[qt][c], Ot[dt][qt]);
      }
    __syncthreads();  // staging of buf[1-p] complete; all waves done with buf[p]
  }

  // final normalizer: lanes {l16, l16+16, l16+32, l16+48} hold q=l16 partials
  float inv[2];
#pragma unroll
  for (int qt = 0; qt < 2; ++qt) {
    float l = lrun[qt];
    l += __shfl_xor(l, 16);
    l += __shfl_xor(l, 32);
    inv[qt] = 1.0f / l;
  }

  // write O^T: per lane q = l16 (fixed), d = dt*16 + quad*4 + r (contiguous)
#pragma unroll
  for (int qt = 0; qt < 2; ++qt) {
    int q = q0 + wave * 32 + qt * 16 + l16;
    size_t ob = ((size_t)b * SS + q) * DM + h * DH;
#pragma unroll
    for (int dt = 0; dt < 4; ++dt) {
      uintx2 o;
      o[0] = pack2bf(Ot[dt][qt][0] * inv[qt], Ot[dt][qt][1] * inv[qt]);
      o[1] = pack2bf(Ot[dt][qt][2] * inv[qt], Ot[dt][qt][3] * inv[qt]);
      *(uintx2*)(&ctx[ob + dt * 16 + quad * 4]) = o;
    }
  }
}

extern "C" void kernel_launch(void* const* d_in, const int* in_sizes, int n_in,
                              void* d_out, int out_size, void* d_ws, size_t ws_size,
                              hipStream_t stream) {
  const float* x  = (const float*)d_in[0];
  const float* Wq = (const float*)d_in[1];
  const float* bq = (const float*)d_in[2];
  const float* Wk = (const float*)d_in[3];
  const float* bk = (const float*)d_in[4];
  const float* Wv = (const float*)d_in[5];
  const float* bv = (const float*)d_in[6];
  const float* Wo = (const float*)d_in[7];
  const float* bo = (const float*)d_in[8];
  float* out = (float*)d_out;

  char* ws = (char*)d_ws;
  u16* xb = (u16*)(ws);                        // 16 MB  [8192,1024] bf16
  u16* Wt = (u16*)(ws + (16u << 20));          //  8 MB  [4096,1024] bf16
  u16* Qb = (u16*)(ws + (24u << 20));          // 16 MB  [B,H,S,Dh] (pre-scaled)
  u16* Kb = (u16*)(ws + (40u << 20));          // 16 MB  [B,H,S,Dh]
  u16* VT = (u16*)(ws + (56u << 20));          // 16 MB  [B,H,Dh,S]
  u16* Cb = (u16*)(ws + (72u << 20));          // 16 MB  [B,S,D] bf16 ctx

  k_cvt_x<<<MROWS * DM / 1024, 256, 0, stream>>>(x, xb);
  k_tw<<<dim3(32, 128), dim3(32, 32), 0, stream>>>(Wq, Wk, Wv, Wo, Wt);
  k_gemm<<<dim3(MROWS / 128, 24), 256, 0, stream>>>(
      xb, Wt, MROWS, 3 * DM, DM, bq, bk, bv, Qb, Kb, VT, nullptr, 1);
  k_attn<<<dim3(SS / 128, NH, BB), 256, 0, stream>>>(Qb, Kb, VT, Cb);
  k_gemm<<<dim3(MROWS / 128, 8), 256, 0, stream>>>(
      Cb, Wt + (size_t)3 * DM * DM, MROWS, DM, DM, bo, nullptr, nullptr,
      nullptr, nullptr, nullptr, out, 0);
}

// Round 7
// 324.430 us; speedup vs baseline: 1.2280x; 1.2280x over previous
//
#include <hip/hip_runtime.h>
#include <hip/hip_bf16.h>

#define DM 1024
#define NH 16
#define DH 64
#define BB 4
#define SS 2048
#define MROWS (BB*SS)   // 8192

typedef unsigned short u16;
typedef short bf16x8 __attribute__((ext_vector_type(8)));
typedef short bf16x4 __attribute__((ext_vector_type(4)));
typedef float f32x4 __attribute__((ext_vector_type(4)));
typedef unsigned uintx2 __attribute__((ext_vector_type(2)));

#define MFMA16(a, b, c) __builtin_amdgcn_mfma_f32_16x16x32_bf16((a), (b), (c), 0, 0, 0)
#define MFMA16K16(a, b, c) __builtin_amdgcn_mfma_f32_16x16x16bf16_1k((a), (b), (c), 0, 0, 0)

__device__ __forceinline__ u16 f2bf(float f) {
  union { float f; unsigned u; } v; v.f = f;
  unsigned u = v.u;
  return (u16)((u + 0x7fffu + ((u >> 16) & 1u)) >> 16);
}

// pack two floats -> u32 of two RNE bf16 (lo = a, hi = b); lowers to
// v_cvt_pk_bf16_f32 when available.
__device__ __forceinline__ unsigned pack2bf(float a, float b) {
  __hip_bfloat162 h = __float22bfloat162_rn(make_float2(a, b));
  unsigned u;
  __builtin_memcpy(&u, &h, 4);
  return u;
}

__device__ __forceinline__ bf16x8 ld_bf8(const u16* p) {
  return *(const bf16x8*)p;
}

// ---------------- convert x (fp32 -> bf16), 4 elems/thread ----------------
__global__ __launch_bounds__(256) void k_cvt_x(const float* __restrict__ x,
                                               u16* __restrict__ xb) {
  int i = (blockIdx.x * 256 + threadIdx.x) * 4;
  float4 v = *(const float4*)(x + i);
  ushort4 o;
  o.x = f2bf(v.x); o.y = f2bf(v.y); o.z = f2bf(v.z); o.w = f2bf(v.w);
  *(ushort4*)(xb + i) = o;
}

// ------------- transpose weights W[K,N] -> Wt[N,K] bf16, 4 segments -------
__global__ __launch_bounds__(1024) void k_tw(const float* __restrict__ Wq,
                                             const float* __restrict__ Wk,
                                             const float* __restrict__ Wv,
                                             const float* __restrict__ Wo,
                                             u16* __restrict__ Wt) {
  __shared__ float t[32][33];
  int k0 = blockIdx.x * 32;
  int seg = blockIdx.y >> 5;
  int n0 = (blockIdx.y & 31) * 32;
  const float* W = seg == 0 ? Wq : seg == 1 ? Wk : seg == 2 ? Wv : Wo;
  int tx = threadIdx.x, ty = threadIdx.y;
  t[ty][tx] = W[(size_t)(k0 + ty) * DM + n0 + tx];
  __syncthreads();
  Wt[(size_t)(seg * DM + n0 + ty) * DM + k0 + tx] = f2bf(t[tx][ty]);
}

// ---------------- GEMM: C[M,N] = A[M,K] * Bt[N,K]^T + bias ----------------
// Staging via global_load_lds width=16 (m97 recipe): LDS [128][32] UNPADDED
// (the DMA writes wave-uniform base + lane*16B; padding would break it).
// mode 0: write fp32 [M,N] to of, bias b0
// mode 1: N=3072 fused QKV; Q scaled by 0.125*log2(e); V written transposed
//         [B,H,Dh,S]; Q/K written [B,H,S,Dh] bf16.
__global__ __launch_bounds__(256) void k_gemm(
    const u16* __restrict__ A, const u16* __restrict__ Bt,
    int M, int N, int K,
    const float* __restrict__ b0, const float* __restrict__ b1,
    const float* __restrict__ b2,
    u16* __restrict__ oq, u16* __restrict__ ok, u16* __restrict__ ov,
    float* __restrict__ of, int mode) {
  __shared__ __align__(16) u16 As[128 * 32];
  __shared__ __align__(16) u16 Bs[128 * 32];
  int tid = threadIdx.x;
  int wave = tid >> 6, lane = tid & 63, quad = lane >> 4, l16 = lane & 15;
  int bm = blockIdx.x * 128, bn = blockIdx.y * 128;
  int wr = (wave >> 1) * 64, wc = (wave & 1) * 64;
  f32x4 acc[4][4] = {};

  // staging: wave w covers rows w*32 .. w*32+31 (2 DMA instrs of 16 rows);
  // lane L -> row_in_chunk = L>>2, col = (L&3)*8  (LDS slot = base + L*16B)
  const u16* ga = A + (size_t)(bm + wave * 32 + (lane >> 2)) * K + (lane & 3) * 8;
  const u16* gb = Bt + (size_t)(bn + wave * 32 + (lane >> 2)) * K + (lane & 3) * 8;
  u16* lda = &As[wave * 1024];
  u16* ldb = &Bs[wave * 1024];

  for (int k0 = 0; k0 < K; k0 += 32) {
#pragma unroll
    for (int i = 0; i < 2; ++i) {
      __builtin_amdgcn_global_load_lds(
          (const __attribute__((address_space(1))) void*)(ga + (size_t)i * 16 * K + k0),
          (__attribute__((address_space(3))) void*)(lda + i * 512), 16, 0, 0);
      __builtin_amdgcn_global_load_lds(
          (const __attribute__((address_space(1))) void*)(gb + (size_t)i * 16 * K + k0),
          (__attribute__((address_space(3))) void*)(ldb + i * 512), 16, 0, 0);
    }
    __syncthreads();
    bf16x8 af[4], bfr[4];
#pragma unroll
    for (int mi = 0; mi < 4; ++mi)
      af[mi] = *(const bf16x8*)(&As[(wr + mi * 16 + l16) * 32 + quad * 8]);
#pragma unroll
    for (int ni = 0; ni < 4; ++ni)
      bfr[ni] = *(const bf16x8*)(&Bs[(wc + ni * 16 + l16) * 32 + quad * 8]);
#pragma unroll
    for (int mi = 0; mi < 4; ++mi)
#pragma unroll
      for (int ni = 0; ni < 4; ++ni)
        acc[mi][ni] = MFMA16(af[mi], bfr[ni], acc[mi][ni]);
    __syncthreads();
  }

  if (mode == 0) {
#pragma unroll
    for (int mi = 0; mi < 4; ++mi)
#pragma unroll
      for (int ni = 0; ni < 4; ++ni)
#pragma unroll
        for (int r = 0; r < 4; ++r) {
          int row = bm + wr + mi * 16 + quad * 4 + r;
          int col = bn + wc + ni * 16 + l16;
          of[(size_t)row * N + col] = acc[mi][ni][r] + b0[col];
        }
  } else {
    int seg = bn >> 10;  // 128-col block never crosses a 1024 segment
    const float* bia = seg == 0 ? b0 : seg == 1 ? b1 : b2;
    int cb = bn & 1023;
    if (seg == 2) {
      // V transposed: [B,H,Dh,S]; 4 consecutive seq rows -> one 8B store
#pragma unroll
      for (int mi = 0; mi < 4; ++mi)
#pragma unroll
        for (int ni = 0; ni < 4; ++ni) {
          int row = bm + wr + mi * 16 + quad * 4;
          int col = cb + wc + ni * 16 + l16;
          float bv_ = bia[col];
          int bb2 = row >> 11, s = row & 2047, hh = col >> 6, dh = col & 63;
          ushort4 o4;
          o4.x = f2bf(acc[mi][ni][0] + bv_);
          o4.y = f2bf(acc[mi][ni][1] + bv_);
          o4.z = f2bf(acc[mi][ni][2] + bv_);
          o4.w = f2bf(acc[mi][ni][3] + bv_);
          *(ushort4*)(&ov[(((size_t)bb2 * NH + hh) * DH + dh) * SS + s]) = o4;
        }
    } else {
      u16* o = seg == 0 ? oq : ok;
      // fold attention scale AND log2(e) into Q so attn uses exp2 directly
      float sc = seg == 0 ? (0.125f * 1.44269504f) : 1.0f;
#pragma unroll
      for (int mi = 0; mi < 4; ++mi)
#pragma unroll
        for (int ni = 0; ni < 4; ++ni)
#pragma unroll
          for (int r = 0; r < 4; ++r) {
            int row = bm + wr + mi * 16 + quad * 4 + r;
            int col = cb + wc + ni * 16 + l16;
            float v = (acc[mi][ni][r] + bia[col]) * sc;
            int bb2 = row >> 11, s = row & 2047, hh = col >> 6, dh = col & 63;
            o[((((size_t)bb2 * NH + hh) * SS) + s) * DH + dh] = f2bf(v);
          }
    }
  }
}

// ---------------- flash attention (transposed-S, register-resident P) -----
// grid: (S/128, NH, BB), block 256 (4 waves, 32 q-rows each)
// VALU-lean version: raw v_exp_f32, packed bf16 cvt, compile-time buffer
// parity (STEP macro) so all LDS addrs are base+literal offsets.
__global__ __launch_bounds__(256) void k_attn(const u16* __restrict__ Q,
                                              const u16* __restrict__ Kg,
                                              const u16* __restrict__ VT,
                                              u16* __restrict__ ctx) {
  __shared__ __align__(16) u16 Ks[2][64][72];
  __shared__ __align__(16) u16 Vts[2][64][72];  // [d][kv]
  int tid = threadIdx.x;
  int wave = tid >> 6, lane = tid & 63, quad = lane >> 4, l16 = lane & 15;
  int q0 = blockIdx.x * 128;
  int h = blockIdx.y, b = blockIdx.z;
  size_t bh = ((size_t)b * NH + h) * SS * DH;
  const u16* Qp = Q + bh + (size_t)(q0 + wave * 32) * DH;
  const u16* Kp = Kg + bh;
  const u16* Vp = VT + ((size_t)b * NH + h) * DH * SS;  // [Dh][S]

  // Q as B-operand fragments: B[k=d=quad*8+j][n=q=l16], 2 q-tiles
  bf16x8 qf[2][2];
#pragma unroll
  for (int qt = 0; qt < 2; ++qt) {
    qf[qt][0] = ld_bf8(Qp + (qt * 16 + l16) * DH + quad * 8);
    qf[qt][1] = ld_bf8(Qp + (qt * 16 + l16) * DH + 32 + quad * 8);
  }

  f32x4 Ot[4][2] = {};           // [d-tile][q-tile], O^T C-layout
  float lrun[2] = {0.0f, 0.0f};  // per-lane partial sums (q = l16)

  int sr = tid >> 3;        // 0..31
  int sc = (tid & 7) * 8;   // 0..56

  // hoisted pointers (all later addressing = base + literal)
  const u16* kfr = &Ks[0][l16][quad * 8];   // + P*4608 + t*1152 (+32 hi)
  const u16* vfr = &Vts[0][l16][0];         // + P*4608 + dt*1152 + c*16 + quad*4
  u16* kst = &Ks[0][sr][sc];                // + (1-P)*4608 + i*2304
  u16* vst = &Vts[0][sr][sc];
  const u16* kg = Kp + (size_t)sr * DH + sc;  // + kv*DH + i*32*DH
  const u16* vg = Vp + (size_t)sr * SS + sc;  // + i*32*SS + kv

  // prestage tile kv=0 into buffer 0
#pragma unroll
  for (int i = 0; i < 2; ++i) {
    *(bf16x8*)(kst + i * 2304) = ld_bf8(kg + i * 32 * DH);
    *(bf16x8*)(vst + i * 2304) = ld_bf8(vg + (size_t)i * 32 * SS);
  }
  __syncthreads();

  int kv = 64;  // next tile to stage

#define ATTN_STEP(P)                                                         \
  {                                                                          \
    f32x4 s[2][4];                                                           \
    _Pragma("unroll") for (int t = 0; t < 4; ++t) {                          \
      bf16x8 kb0 = *(const bf16x8*)(kfr + (P) * 4608 + t * 1152);            \
      bf16x8 kb1 = *(const bf16x8*)(kfr + (P) * 4608 + t * 1152 + 32);       \
      _Pragma("unroll") for (int qt = 0; qt < 2; ++qt) {                     \
        f32x4 z = {};                                                        \
        z = MFMA16(kb0, qf[qt][0], z);                                       \
        z = MFMA16(kb1, qf[qt][1], z);                                       \
        s[qt][t] = z;                                                        \
      }                                                                      \
    }                                                                        \
    if (kv < SS) {                                                           \
      _Pragma("unroll") for (int i = 0; i < 2; ++i) {                        \
        *(bf16x8*)(kst + (1 - (P)) * 4608 + i * 2304) =                      \
            ld_bf8(kg + (size_t)kv * DH + i * 32 * DH);                      \
        *(bf16x8*)(vst + (1 - (P)) * 4608 + i * 2304) =                      \
            ld_bf8(vg + (size_t)i * 32 * SS + kv);                           \
      }                                                                      \
    }                                                                        \
    bf16x4 pb[2][4];                                                         \
    _Pragma("unroll") for (int qt = 0; qt < 2; ++qt)                         \
        _Pragma("unroll") for (int t = 0; t < 4; ++t) {                      \
      float e0 = __builtin_amdgcn_exp2f(s[qt][t][0]);                        \
      float e1 = __builtin_amdgcn_exp2f(s[qt][t][1]);                        \
      float e2 = __builtin_amdgcn_exp2f(s[qt][t][2]);                        \
      float e3 = __builtin_amdgcn_exp2f(s[qt][t][3]);                        \
      lrun[qt] += (e0 + e1) + (e2 + e3);                                     \
      uintx2 w;                                                              \
      w[0] = pack2bf(e0, e1);                                                \
      w[1] = pack2bf(e2, e3);                                                \
      pb[qt][t] = __builtin_bit_cast(bf16x4, w);                             \
    }                                                                        \
    _Pragma("unroll") for (int c = 0; c < 4; ++c)                            \
        _Pragma("unroll") for (int dt = 0; dt < 4; ++dt) {                   \
      bf16x4 va = *(const bf16x4*)(vfr + (P) * 4608 + dt * 1152 + c * 16 +   \
                                   quad * 4);                                \
      _Pragma("unroll") for (int qt = 0; qt < 2; ++qt)                       \
          Ot[dt][qt] = MFMA16K16(va, pb[qt][c], Ot[dt][qt]);                 \
    }                                                                        \
    __syncthreads();                                                         \
    kv += 64;                                                                \
  }

  for (int it = 0; it < SS / 128; ++it) {
    ATTN_STEP(0);
    ATTN_STEP(1);
  }
#undef ATTN_STEP

  // final normalizer: lanes {l16, +16, +32, +48} hold q=l16 partials
  float inv[2];
#pragma unroll
  for (int qt = 0; qt < 2; ++qt) {
    float l = lrun[qt];
    l += __shfl_xor(l, 16);
    l += __shfl_xor(l, 32);
    inv[qt] = 1.0f / l;
  }

  // write O^T: per lane q = l16 (fixed), d = dt*16 + quad*4 + r (contiguous)
#pragma unroll
  for (int qt = 0; qt < 2; ++qt) {
    int q = q0 + wave * 32 + qt * 16 + l16;
    size_t ob = ((size_t)b * SS + q) * DM + h * DH;
#pragma unroll
    for (int dt = 0; dt < 4; ++dt) {
      uintx2 o;
      o[0] = pack2bf(Ot[dt][qt][0] * inv[qt], Ot[dt][qt][1] * inv[qt]);
      o[1] = pack2bf(Ot[dt][qt][2] * inv[qt], Ot[dt][qt][3] * inv[qt]);
      *(uintx2*)(&ctx[ob + dt * 16 + quad * 4]) = o;
    }
  }
}

extern "C" void kernel_launch(void* const* d_in, const int* in_sizes, int n_in,
                              void* d_out, int out_size, void* d_ws, size_t ws_size,
                              hipStream_t stream) {
  const float* x  = (const float*)d_in[0];
  const float* Wq = (const float*)d_in[1];
  const float* bq = (const float*)d_in[2];
  const float* Wk = (const float*)d_in[3];
  const float* bk = (const float*)d_in[4];
  const float* Wv = (const float*)d_in[5];
  const float* bv = (const float*)d_in[6];
  const float* Wo = (const float*)d_in[7];
  const float* bo = (const float*)d_in[8];
  float* out = (float*)d_out;

  char* ws = (char*)d_ws;
  u16* xb = (u16*)(ws);                        // 16 MB  [8192,1024] bf16
  u16* Wt = (u16*)(ws + (16u << 20));          //  8 MB  [4096,1024] bf16
  u16* Qb = (u16*)(ws + (24u << 20));          // 16 MB  [B,H,S,Dh] (pre-scaled)
  u16* Kb = (u16*)(ws + (40u << 20));          // 16 MB  [B,H,S,Dh]
  u16* VT = (u16*)(ws + (56u << 20));          // 16 MB  [B,H,Dh,S]
  u16* Cb = (u16*)(ws + (72u << 20));          // 16 MB  [B,S,D] bf16 ctx

  k_cvt_x<<<MROWS * DM / 1024, 256, 0, stream>>>(x, xb);
  k_tw<<<dim3(32, 128), dim3(32, 32), 0, stream>>>(Wq, Wk, Wv, Wo, Wt);
  k_gemm<<<dim3(MROWS / 128, 24), 256, 0, stream>>>(
      xb, Wt, MROWS, 3 * DM, DM, bq, bk, bv, Qb, Kb, VT, nullptr, 1);
  k_attn<<<dim3(SS / 128, NH, BB), 256, 0, stream>>>(Qb, Kb, VT, Cb);
  k_gemm<<<dim3(MROWS / 128, 8), 256, 0, stream>>>(
      Cb, Wt + (size_t)3 * DM * DM, MROWS, DM, DM, bo, nullptr, nullptr,
      nullptr, nullptr, nullptr, out, 0);
}

// Round 8
// 316.415 us; speedup vs baseline: 1.2591x; 1.0253x over previous
//
#include <hip/hip_runtime.h>
#include <hip/hip_bf16.h>

#define DM 1024
#define NH 16
#define DH 64
#define BB 4
#define SS 2048
#define MROWS (BB*SS)   // 8192

typedef unsigned short u16;
typedef short bf16x8 __attribute__((ext_vector_type(8)));
typedef short bf16x4 __attribute__((ext_vector_type(4)));
typedef float f32x4 __attribute__((ext_vector_type(4)));
typedef unsigned uintx2 __attribute__((ext_vector_type(2)));

#define MFMA16(a, b, c) __builtin_amdgcn_mfma_f32_16x16x32_bf16((a), (b), (c), 0, 0, 0)
#define MFMA16K16(a, b, c) __builtin_amdgcn_mfma_f32_16x16x16bf16_1k((a), (b), (c), 0, 0, 0)

__device__ __forceinline__ u16 f2bf(float f) {
  union { float f; unsigned u; } v; v.f = f;
  unsigned u = v.u;
  return (u16)((u + 0x7fffu + ((u >> 16) & 1u)) >> 16);
}

// pack two floats -> u32 of two RNE bf16 (lo = a, hi = b)
__device__ __forceinline__ unsigned pack2bf(float a, float b) {
  __hip_bfloat162 h = __float22bfloat162_rn(make_float2(a, b));
  unsigned u;
  __builtin_memcpy(&u, &h, 4);
  return u;
}

__device__ __forceinline__ bf16x8 ld_bf8(const u16* p) {
  return *(const bf16x8*)p;
}

// ---------------- convert x (fp32 -> bf16), 4 elems/thread ----------------
__global__ __launch_bounds__(256) void k_cvt_x(const float* __restrict__ x,
                                               u16* __restrict__ xb) {
  int i = (blockIdx.x * 256 + threadIdx.x) * 4;
  float4 v = *(const float4*)(x + i);
  ushort4 o;
  o.x = f2bf(v.x); o.y = f2bf(v.y); o.z = f2bf(v.z); o.w = f2bf(v.w);
  *(ushort4*)(xb + i) = o;
}

// ------------- transpose weights W[K,N] -> Wt[N,K] bf16, 4 segments -------
__global__ __launch_bounds__(1024) void k_tw(const float* __restrict__ Wq,
                                             const float* __restrict__ Wk,
                                             const float* __restrict__ Wv,
                                             const float* __restrict__ Wo,
                                             u16* __restrict__ Wt) {
  __shared__ float t[32][33];
  int k0 = blockIdx.x * 32;
  int seg = blockIdx.y >> 5;
  int n0 = (blockIdx.y & 31) * 32;
  const float* W = seg == 0 ? Wq : seg == 1 ? Wk : seg == 2 ? Wv : Wo;
  int tx = threadIdx.x, ty = threadIdx.y;
  t[ty][tx] = W[(size_t)(k0 + ty) * DM + n0 + tx];
  __syncthreads();
  Wt[(size_t)(seg * DM + n0 + ty) * DM + k0 + tx] = f2bf(t[tx][ty]);
}

// ---------------- GEMM: C[M,N] = A[M,K] * Bt[N,K]^T + bias ----------------
// (unchanged from R7)
__global__ __launch_bounds__(256) void k_gemm(
    const u16* __restrict__ A, const u16* __restrict__ Bt,
    int M, int N, int K,
    const float* __restrict__ b0, const float* __restrict__ b1,
    const float* __restrict__ b2,
    u16* __restrict__ oq, u16* __restrict__ ok, u16* __restrict__ ov,
    float* __restrict__ of, int mode) {
  __shared__ __align__(16) u16 As[128 * 32];
  __shared__ __align__(16) u16 Bs[128 * 32];
  int tid = threadIdx.x;
  int wave = tid >> 6, lane = tid & 63, quad = lane >> 4, l16 = lane & 15;
  int bm = blockIdx.x * 128, bn = blockIdx.y * 128;
  int wr = (wave >> 1) * 64, wc = (wave & 1) * 64;
  f32x4 acc[4][4] = {};

  const u16* ga = A + (size_t)(bm + wave * 32 + (lane >> 2)) * K + (lane & 3) * 8;
  const u16* gb = Bt + (size_t)(bn + wave * 32 + (lane >> 2)) * K + (lane & 3) * 8;
  u16* lda = &As[wave * 1024];
  u16* ldb = &Bs[wave * 1024];

  for (int k0 = 0; k0 < K; k0 += 32) {
#pragma unroll
    for (int i = 0; i < 2; ++i) {
      __builtin_amdgcn_global_load_lds(
          (const __attribute__((address_space(1))) void*)(ga + (size_t)i * 16 * K + k0),
          (__attribute__((address_space(3))) void*)(lda + i * 512), 16, 0, 0);
      __builtin_amdgcn_global_load_lds(
          (const __attribute__((address_space(1))) void*)(gb + (size_t)i * 16 * K + k0),
          (__attribute__((address_space(3))) void*)(ldb + i * 512), 16, 0, 0);
    }
    __syncthreads();
    bf16x8 af[4], bfr[4];
#pragma unroll
    for (int mi = 0; mi < 4; ++mi)
      af[mi] = *(const bf16x8*)(&As[(wr + mi * 16 + l16) * 32 + quad * 8]);
#pragma unroll
    for (int ni = 0; ni < 4; ++ni)
      bfr[ni] = *(const bf16x8*)(&Bs[(wc + ni * 16 + l16) * 32 + quad * 8]);
#pragma unroll
    for (int mi = 0; mi < 4; ++mi)
#pragma unroll
      for (int ni = 0; ni < 4; ++ni)
        acc[mi][ni] = MFMA16(af[mi], bfr[ni], acc[mi][ni]);
    __syncthreads();
  }

  if (mode == 0) {
#pragma unroll
    for (int mi = 0; mi < 4; ++mi)
#pragma unroll
      for (int ni = 0; ni < 4; ++ni)
#pragma unroll
        for (int r = 0; r < 4; ++r) {
          int row = bm + wr + mi * 16 + quad * 4 + r;
          int col = bn + wc + ni * 16 + l16;
          of[(size_t)row * N + col] = acc[mi][ni][r] + b0[col];
        }
  } else {
    int seg = bn >> 10;
    const float* bia = seg == 0 ? b0 : seg == 1 ? b1 : b2;
    int cb = bn & 1023;
    if (seg == 2) {
#pragma unroll
      for (int mi = 0; mi < 4; ++mi)
#pragma unroll
        for (int ni = 0; ni < 4; ++ni) {
          int row = bm + wr + mi * 16 + quad * 4;
          int col = cb + wc + ni * 16 + l16;
          float bv_ = bia[col];
          int bb2 = row >> 11, s = row & 2047, hh = col >> 6, dh = col & 63;
          ushort4 o4;
          o4.x = f2bf(acc[mi][ni][0] + bv_);
          o4.y = f2bf(acc[mi][ni][1] + bv_);
          o4.z = f2bf(acc[mi][ni][2] + bv_);
          o4.w = f2bf(acc[mi][ni][3] + bv_);
          *(ushort4*)(&ov[(((size_t)bb2 * NH + hh) * DH + dh) * SS + s]) = o4;
        }
    } else {
      u16* o = seg == 0 ? oq : ok;
      float sc = seg == 0 ? (0.125f * 1.44269504f) : 1.0f;
#pragma unroll
      for (int mi = 0; mi < 4; ++mi)
#pragma unroll
        for (int ni = 0; ni < 4; ++ni)
#pragma unroll
          for (int r = 0; r < 4; ++r) {
            int row = bm + wr + mi * 16 + quad * 4 + r;
            int col = cb + wc + ni * 16 + l16;
            float v = (acc[mi][ni][r] + bia[col]) * sc;
            int bb2 = row >> 11, s = row & 2047, hh = col >> 6, dh = col & 63;
            o[((((size_t)bb2 * NH + hh) * SS) + s) * DH + dh] = f2bf(v);
          }
    }
  }
}

// ---------------- flash attention (transposed-S, register P, DMA staging) --
// grid: (S/128, NH, BB), block 256 (4 waves, 32 q-rows each)
// K/V staged via global_load_lds width=16 into XOR-swizzled [64][64] tiles:
// LDS slot (row, cb) holds global (row, cb ^ (row&7)); swizzle is applied on
// the global-address side (DMA lands lane L at base + L*16B, fixed). With
// this swizzle both the QK b128 frag reads and the PV b64 frag reads hit the
// LDS bank floor (verified by hand: 8 and 4 words/bank resp.).
// P pack: v_perm_b32 RTZ (1 instr / 2 values); lrun accumulates the
// TRUNCATED values so PV numerator and normalizer are self-consistent.
__global__ __launch_bounds__(256) void k_attn(const u16* __restrict__ Q,
                                              const u16* __restrict__ Kg,
                                              const u16* __restrict__ VT,
                                              u16* __restrict__ ctx) {
  __shared__ __align__(16) u16 Ks[2][64][64];
  __shared__ __align__(16) u16 Vts[2][64][64];  // [d][kv], swizzled
  int tid = threadIdx.x;
  int wave = tid >> 6, lane = tid & 63, quad = lane >> 4, l16 = lane & 15;
  int q0 = blockIdx.x * 128;
  int h = blockIdx.y, b = blockIdx.z;
  size_t bh = ((size_t)b * NH + h) * SS * DH;
  const u16* Qp = Q + bh + (size_t)(q0 + wave * 32) * DH;
  const u16* Kp = Kg + bh;
  const u16* Vp = VT + ((size_t)b * NH + h) * DH * SS;  // [Dh][S]

  // Q as B-operand fragments: B[k=d=quad*8+j][n=q=l16], 2 q-tiles
  bf16x8 qf[2][2];
#pragma unroll
  for (int qt = 0; qt < 2; ++qt) {
    qf[qt][0] = ld_bf8(Qp + (qt * 16 + l16) * DH + quad * 8);
    qf[qt][1] = ld_bf8(Qp + (qt * 16 + l16) * DH + 32 + quad * 8);
  }

  f32x4 Ot[4][2] = {};           // [d-tile][q-tile], O^T C-layout
  float lrun[2] = {0.0f, 0.0f};  // per-lane partial sums (q = l16)

  // ---- staging constants (global side carries the swizzle) ----
  int lrow = lane >> 3;            // 0..7 (row within 8-row DMA chunk)
  int lcb = (lane & 7) ^ lrow;     // swizzled global col-block
  const u16* kdma[2];
  const u16* vdma[2];
  u16* kl[2];
  u16* vl[2];
#pragma unroll
  for (int i = 0; i < 2; ++i) {
    int chunk = wave * 2 + i;      // 0..7, 8 rows each
    kdma[i] = Kp + (size_t)(chunk * 8 + lrow) * DH + lcb * 8;
    vdma[i] = Vp + (size_t)(chunk * 8 + lrow) * SS + lcb * 8;
    kl[i] = &Ks[0][chunk * 8][0];
    vl[i] = &Vts[0][chunk * 8][0];
  }

  // ---- hoisted frag pointers (loop addressing = base + literal) ----
  int e7 = l16 & 7, qh = quad >> 1, qp = quad & 1;
  const u16* kfr0 = &Ks[0][l16][(quad ^ e7) * 8];        // d-blocks 0..3
  const u16* kfr1 = &Ks[0][l16][((quad + 4) ^ e7) * 8];  // d-blocks 4..7
  const u16* vfr[4];
#pragma unroll
  for (int c = 0; c < 4; ++c)
    vfr[c] = &Vts[0][l16][((2 * c + qh) ^ e7) * 8 + qp * 4];

  // ---- prestage tile kv=0 into buffer 0 ----
#pragma unroll
  for (int i = 0; i < 2; ++i) {
    __builtin_amdgcn_global_load_lds(
        (const __attribute__((address_space(1))) void*)kdma[i],
        (__attribute__((address_space(3))) void*)kl[i], 16, 0, 0);
    __builtin_amdgcn_global_load_lds(
        (const __attribute__((address_space(1))) void*)vdma[i],
        (__attribute__((address_space(3))) void*)vl[i], 16, 0, 0);
  }
  __syncthreads();

  int kv = 64;  // next tile to stage

#define ATTN_STEP(P)                                                          \
  {                                                                           \
    f32x4 s[2][4];                                                            \
    _Pragma("unroll") for (int t = 0; t < 4; ++t) {                           \
      bf16x8 kb0 = *(const bf16x8*)(kfr0 + (P) * 4096 + t * 1024);            \
      bf16x8 kb1 = *(const bf16x8*)(kfr1 + (P) * 4096 + t * 1024);            \
      _Pragma("unroll") for (int qt = 0; qt < 2; ++qt) {                      \
        f32x4 z = {};                                                         \
        z = MFMA16(kb0, qf[qt][0], z);                                        \
        z = MFMA16(kb1, qf[qt][1], z);                                        \
        s[qt][t] = z;                                                         \
      }                                                                       \
    }                                                                         \
    if (kv < SS) {                                                            \
      _Pragma("unroll") for (int i = 0; i < 2; ++i) {                         \
        __builtin_amdgcn_global_load_lds(                                     \
            (const __attribute__((address_space(1))) void*)(kdma[i] +         \
                                                            (size_t)kv * DH), \
            (__attribute__((address_space(3))) void*)(kl[i] +                 \
                                                      (1 - (P)) * 4096),      \
            16, 0, 0);                                                        \
        __builtin_amdgcn_global_load_lds(                                     \
            (const __attribute__((address_space(1))) void*)(vdma[i] + kv),    \
            (__attribute__((address_space(3))) void*)(vl[i] +                 \
                                                      (1 - (P)) * 4096),      \
            16, 0, 0);                                                        \
      }                                                                       \
    }                                                                         \
    bf16x4 pb[2][4];                                                          \
    _Pragma("unroll") for (int qt = 0; qt < 2; ++qt)                          \
        _Pragma("unroll") for (int t = 0; t < 4; ++t) {                       \
      unsigned u0 = __builtin_bit_cast(                                       \
          unsigned, __builtin_amdgcn_exp2f(s[qt][t][0]));                     \
      unsigned u1 = __builtin_bit_cast(                                       \
          unsigned, __builtin_amdgcn_exp2f(s[qt][t][1]));                     \
      unsigned u2 = __builtin_bit_cast(                                       \
          unsigned, __builtin_amdgcn_exp2f(s[qt][t][2]));                     \
      unsigned u3 = __builtin_bit_cast(                                       \
          unsigned, __builtin_amdgcn_exp2f(s[qt][t][3]));                     \
      unsigned w0 = __builtin_amdgcn_perm(u1, u0, 0x07060302u);               \
      unsigned w1 = __builtin_amdgcn_perm(u3, u2, 0x07060302u);               \
      lrun[qt] += __builtin_bit_cast(float, w0 << 16) +                       \
                  __builtin_bit_cast(float, w0 & 0xffff0000u) +               \
                  __builtin_bit_cast(float, w1 << 16) +                       \
                  __builtin_bit_cast(float, w1 & 0xffff0000u);                \
      uintx2 w;                                                               \
      w[0] = w0;                                                              \
      w[1] = w1;                                                              \
      pb[qt][t] = __builtin_bit_cast(bf16x4, w);                              \
    }                                                                         \
    _Pragma("unroll") for (int c = 0; c < 4; ++c)                             \
        _Pragma("unroll") for (int dt = 0; dt < 4; ++dt) {                    \
      bf16x4 va = *(const bf16x4*)(vfr[c] + (P) * 4096 + dt * 1024);          \
      _Pragma("unroll") for (int qt = 0; qt < 2; ++qt)                        \
          Ot[dt][qt] = MFMA16K16(va, pb[qt][c], Ot[dt][qt]);                  \
    }                                                                         \
    __syncthreads();                                                          \
    kv += 64;                                                                 \
  }

  for (int it = 0; it < SS / 128; ++it) {
    ATTN_STEP(0);
    ATTN_STEP(1);
  }
#undef ATTN_STEP

  // final normalizer: lanes {l16, +16, +32, +48} hold q=l16 partials
  float inv[2];
#pragma unroll
  for (int qt = 0; qt < 2; ++qt) {
    float l = lrun[qt];
    l += __shfl_xor(l, 16);
    l += __shfl_xor(l, 32);
    inv[qt] = 1.0f / l;
  }

  // write O^T: per lane q = l16 (fixed), d = dt*16 + quad*4 + r (contiguous)
#pragma unroll
  for (int qt = 0; qt < 2; ++qt) {
    int q = q0 + wave * 32 + qt * 16 + l16;
    size_t ob = ((size_t)b * SS + q) * DM + h * DH;
#pragma unroll
    for (int dt = 0; dt < 4; ++dt) {
      uintx2 o;
      o[0] = pack2bf(Ot[dt][qt][0] * inv[qt], Ot[dt][qt][1] * inv[qt]);
      o[1] = pack2bf(Ot[dt][qt][2] * inv[qt], Ot[dt][qt][3] * inv[qt]);
      *(uintx2*)(&ctx[ob + dt * 16 + quad * 4]) = o;
    }
  }
}

extern "C" void kernel_launch(void* const* d_in, const int* in_sizes, int n_in,
                              void* d_out, int out_size, void* d_ws, size_t ws_size,
                              hipStream_t stream) {
  const float* x  = (const float*)d_in[0];
  const float* Wq = (const float*)d_in[1];
  const float* bq = (const float*)d_in[2];
  const float* Wk = (const float*)d_in[3];
  const float* bk = (const float*)d_in[4];
  const float* Wv = (const float*)d_in[5];
  const float* bv = (const float*)d_in[6];
  const float* Wo = (const float*)d_in[7];
  const float* bo = (const float*)d_in[8];
  float* out = (float*)d_out;

  char* ws = (char*)d_ws;
  u16* xb = (u16*)(ws);                        // 16 MB  [8192,1024] bf16
  u16* Wt = (u16*)(ws + (16u << 20));          //  8 MB  [4096,1024] bf16
  u16* Qb = (u16*)(ws + (24u << 20));          // 16 MB  [B,H,S,Dh] (pre-scaled)
  u16* Kb = (u16*)(ws + (40u << 20));          // 16 MB  [B,H,S,Dh]
  u16* VT = (u16*)(ws + (56u << 20));          // 16 MB  [B,H,Dh,S]
  u16* Cb = (u16*)(ws + (72u << 20));          // 16 MB  [B,S,D] bf16 ctx

  k_cvt_x<<<MROWS * DM / 1024, 256, 0, stream>>>(x, xb);
  k_tw<<<dim3(32, 128), dim3(32, 32), 0, stream>>>(Wq, Wk, Wv, Wo, Wt);
  k_gemm<<<dim3(MROWS / 128, 24), 256, 0, stream>>>(
      xb, Wt, MROWS, 3 * DM, DM, bq, bk, bv, Qb, Kb, VT, nullptr, 1);
  k_attn<<<dim3(SS / 128, NH, BB), 256, 0, stream>>>(Qb, Kb, VT, Cb);
  k_gemm<<<dim3(MROWS / 128, 8), 256, 0, stream>>>(
      Cb, Wt + (size_t)3 * DM * DM, MROWS, DM, DM, bo, nullptr, nullptr,
      nullptr, nullptr, nullptr, out, 0);
}